// Round 2
// baseline (341.292 us; speedup 1.0000x reference)
//
#include <hip/hip_runtime.h>
#include <hip/hip_bf16.h>

#define B_  32
#define N_  2048
#define M_  2048
#define D_  128

typedef __attribute__((ext_vector_type(4)))  float f32x4;
typedef __attribute__((ext_vector_type(8)))  short bf16x8;

// log2(e) / sqrt(128): softmax in exp2 domain; folded into Q's bf16 cast.
static constexpr float SCALE2 = 1.4426950408889634f / 11.313708498984761f;

__device__ __forceinline__ unsigned short f2bf(float x) {
  union { float f; unsigned u; } c; c.f = x;
  unsigned u = c.u;
  return (unsigned short)((u + 0x7FFFu + ((u >> 16) & 1u)) >> 16);  // RNE
}

__device__ __forceinline__ unsigned pk2bf(float a, float b) {
  float2 f2; f2.x = a; f2.y = b;
  __hip_bfloat162 h = __float22bfloat162_rn(f2);   // v_cvt_pk_bf16_f32
  union { __hip_bfloat162 h; unsigned u; } c; c.h = h;
  return c.u;
}

__device__ __forceinline__ float fexp2(float x) {
#if __has_builtin(__builtin_amdgcn_exp2f)
  return __builtin_amdgcn_exp2f(x);
#else
  float r; asm("v_exp_f32 %0, %1" : "=v"(r) : "v"(x)); return r;
#endif
}
__device__ __forceinline__ float flog2(float x) {
#if __has_builtin(__builtin_amdgcn_logf)
  return __builtin_amdgcn_logf(x);
#else
  float r; asm("v_log_f32 %0, %1" : "=v"(r) : "v"(x)); return r;
#endif
}

// async global->LDS, 16B per lane; LDS dest = wave-uniform base + lane*16
__device__ __forceinline__ void gl2lds16(const void* gp, void* lp) {
  __builtin_amdgcn_global_load_lds(
      (const __attribute__((address_space(1))) unsigned int*)gp,
      (__attribute__((address_space(3))) unsigned int*)lp, 16, 0, 0);
}

// ---------- prep (one dispatch): cast Q (SCALE2), cast K, transpose V, zero colsum ----------
// blocks [0,2048): Q cast; [2048,4096): K cast (64B load / 32B store per thread);
// [4096,6144): V transpose.
__global__ __launch_bounds__(256) void prep_kernel(
    const float* __restrict__ Q, const float* __restrict__ K,
    const float* __restrict__ V, unsigned short* __restrict__ Qb,
    unsigned short* __restrict__ Kb, unsigned short* __restrict__ Vt,
    float* __restrict__ colsum) {
  const int blk = blockIdx.x;
  if (blk < 4096) {
    const int i = (blk & 2047) * 256 + threadIdx.x;   // 64B-group idx, < 524288
    if (blk < 64) {
      const int j = blk * 256 + threadIdx.x;          // < 16384 == B_*M_/4
      reinterpret_cast<float4*>(colsum)[j] = make_float4(0.f, 0.f, 0.f, 0.f);
    }
    const bool isK = blk >= 2048;
    const float4* src = reinterpret_cast<const float4*>(isK ? K : Q);
    uint4* dst = reinterpret_cast<uint4*>(isK ? Kb : Qb);
    const float sc = isK ? 1.0f : SCALE2;
    #pragma unroll
    for (int h = 0; h < 2; ++h) {
      const float4 v0 = src[4 * i + 2 * h];
      const float4 v1 = src[4 * i + 2 * h + 1];
      uint4 o;
      o.x = pk2bf(v0.x * sc, v0.y * sc);
      o.y = pk2bf(v0.z * sc, v0.w * sc);
      o.z = pk2bf(v1.x * sc, v1.y * sc);
      o.w = pk2bf(v1.z * sc, v1.w * sc);
      dst[2 * i + h] = o;
    }
    return;
  }
  // V transpose: idx -> (b, m0, d0); 2048 blocks = (M/64=32) x (D/64=2) x (B=32)
  const int idx = blk - 4096;
  const int b  = idx >> 6;
  const int m0 = ((idx >> 1) & 31) * 64;
  const int d0 = (idx & 1) * 64;
  __shared__ float t[64][65];
  const int tid = threadIdx.x;
  const int r = tid >> 2;   // 0..63
  const int c = tid & 3;    // 0..3
  const float* src = V + ((size_t)b * M_ + (m0 + r)) * D_ + d0 + c * 16;
  #pragma unroll
  for (int i = 0; i < 4; ++i) {
    float4 v = reinterpret_cast<const float4*>(src)[i];
    t[r][c * 16 + i * 4 + 0] = v.x;
    t[r][c * 16 + i * 4 + 1] = v.y;
    t[r][c * 16 + i * 4 + 2] = v.z;
    t[r][c * 16 + i * 4 + 3] = v.w;
  }
  __syncthreads();
  ushort4 ob[4];
  #pragma unroll
  for (int i = 0; i < 4; ++i) {
    ob[i].x = f2bf(t[c * 16 + i * 4 + 0][r]);
    ob[i].y = f2bf(t[c * 16 + i * 4 + 1][r]);
    ob[i].z = f2bf(t[c * 16 + i * 4 + 2][r]);
    ob[i].w = f2bf(t[c * 16 + i * 4 + 3][r]);
  }
  ushort4* dst = reinterpret_cast<ushort4*>(
      Vt + ((size_t)b * D_ + d0 + r) * M_ + m0 + c * 16);
  #pragma unroll
  for (int i = 0; i < 4; ++i) dst[i] = ob[i];
}

// ---------- pass 1: colsum[b][m] += sum_{n in quarter} 2^(s2[n,m]-16) ----------
// 1024 blocks (4/CU, 16 waves/CU): id = x*128 + (b*4+y); id%8 == (4b+y)%8 so the
// 8 m-blocks sharing a (b, n-quarter) Q stripe (128KB) co-reside on one XCD.
// 8 chunks of 64 n, double-buffered 2-phase staging; even/odd acc pipelining so
// exp2(ng) overlaps MFMA(ng+1) in the matrix pipe.
__global__ __launch_bounds__(256, 4) void colstats_v8_kernel(
    const unsigned short* __restrict__ Qb, const unsigned short* __restrict__ Kb,
    float* __restrict__ colsum) {
  const int id   = blockIdx.x;          // 0..1023
  const int x    = id >> 7;             // m-block 0..7
  const int q    = id & 127;
  const int b    = q >> 2;
  const int y    = q & 3;               // n-quarter
  const int lane = threadIdx.x & 63;
  const int l15  = lane & 15;
  const int quad = lane >> 4;
  const int mw   = x * 256 + (threadIdx.x >> 6) * 64;
  const int nbase = y * (N_ / 4);       // 512-n stripe

  __shared__ unsigned short qbuf[2][64 * 128];  // 2 x 16 KB; rows n, chunk c^(n&15)

  // B-operand: B[col=m=mw+cg*16+l15][k=quad*8+j (+kc*32)] — 64 VGPRs
  bf16x8 kf[4][4];
  #pragma unroll
  for (int cg = 0; cg < 4; ++cg) {
    const unsigned short* Kr =
        Kb + ((size_t)b * M_ + mw + cg * 16 + l15) * D_ + quad * 8;
    #pragma unroll
    for (int kc = 0; kc < 4; ++kc)
      kf[cg][kc] = *reinterpret_cast<const bf16x8*>(Kr + kc * 32);
  }

  // hoisted LDS read bases: addr = pq[kc] + cb*8192 + ng*2048 (u16)
  const unsigned short* pq[4];
  #pragma unroll
  for (int kc = 0; kc < 4; ++kc)
    pq[kc] = qbuf[0] + l15 * 128 + (((kc * 4 + quad) ^ l15) * 8);

  // running DMA source pointers (4 slots/thread), constant LDS dests
  const unsigned short* qg[4];
  unsigned short* ql[4];
  #pragma unroll
  for (int i = 0; i < 4; ++i) {
    int s = i * 256 + threadIdx.x;             // 16B slot 0..1023
    int r = s >> 4, c = (s & 15) ^ (r & 15);
    qg[i] = Qb + ((size_t)b * N_ + nbase + r) * D_ + c * 8;
    ql[i] = qbuf[0] + (size_t)s * 8;           // s*16 bytes
  }

  float psum[4] = {0.f, 0.f, 0.f, 0.f};

#define CS_STAGE(nb)                                                          \
  { _Pragma("unroll")                                                         \
    for (int i = 0; i < 4; ++i) {                                             \
      gl2lds16(qg[i], ql[i] + (nb) * (64 * 128));                             \
      qg[i] += 64 * D_;                                                       \
    } }

#define CS_QK(cb, ng, acc)                                                    \
  { __builtin_amdgcn_s_setprio(1);                                            \
    _Pragma("unroll")                                                         \
    for (int kc = 0; kc < 4; ++kc) {                                          \
      bf16x8 af = *reinterpret_cast<const bf16x8*>(                           \
          pq[kc] + (cb) * (64 * 128) + (ng) * 2048);                          \
      _Pragma("unroll")                                                       \
      for (int cg = 0; cg < 4; ++cg)                                          \
        acc[cg] = __builtin_amdgcn_mfma_f32_16x16x32_bf16(                    \
            af, kf[cg][kc], acc[cg], 0, 0, 0);                                \
    }                                                                         \
    __builtin_amdgcn_s_setprio(0); }

#define CS_EXP(acc)                                                           \
  { _Pragma("unroll")                                                         \
    for (int cg = 0; cg < 4; ++cg)                                            \
      psum[cg] += fexp2(acc[cg][0] - 16.f) + fexp2(acc[cg][1] - 16.f) +       \
                  fexp2(acc[cg][2] - 16.f) + fexp2(acc[cg][3] - 16.f); }

#define CS_ZERO(acc)                                                          \
  { _Pragma("unroll")                                                         \
    for (int cg = 0; cg < 4; ++cg) acc[cg] = (f32x4){0.f,0.f,0.f,0.f}; }

  // pipelined chunk: exp2 of previous ng overlaps MFMA drain of current ng
#define CS_COMPUTE(cb)                                                        \
  { f32x4 a0[4], a1[4];                                                       \
    CS_ZERO(a0); CS_QK(cb, 0, a0);                                            \
    CS_ZERO(a1); CS_QK(cb, 1, a1); CS_EXP(a0);                                \
    CS_ZERO(a0); CS_QK(cb, 2, a0); CS_EXP(a1);                                \
    CS_ZERO(a1); CS_QK(cb, 3, a1); CS_EXP(a0);                                \
    CS_EXP(a1); }

  CS_STAGE(0);                                 // chunk 0
  __syncthreads();
  #pragma unroll 1
  for (int it = 0; it < 8; it += 2) {
    CS_STAGE(1);                               // chunk it+1 (<=7 always)
    CS_COMPUTE(0);
    __syncthreads();                           // chunk it+1 landed; buf0 free
    if (it + 2 < 8) CS_STAGE(0);               // chunk it+2
    CS_COMPUTE(1);
    __syncthreads();
  }
#undef CS_STAGE
#undef CS_QK
#undef CS_EXP
#undef CS_ZERO
#undef CS_COMPUTE

  #pragma unroll
  for (int cg = 0; cg < 4; ++cg) {
    psum[cg] += __shfl_xor(psum[cg], 16);
    psum[cg] += __shfl_xor(psum[cg], 32);
  }
  if (quad == 0) {
    #pragma unroll
    for (int cg = 0; cg < 4; ++cg)
      atomicAdd(colsum + (size_t)b * M_ + mw + cg * 16 + l15, psum[cg]);
  }
}

// ---------- pass 2: O[n,d] = sum_m 2^(s2[n,m]-cml[m]) * Vt[d,m] ----------
// 512 blocks, XCD-swizzled (id%8==b%8). 64-m chunks, double-buffered K/V LDS,
// one barrier per chunk. T15 software pipeline within each chunk: issue order
// QKT(0) -> SM(0) -> QKT(1) -> PV(0) -> SM(1) -> PV(1), so softmax VALU (which
// stalls on sacc) overlaps the matrix-pipe drain of the previously issued MFMA
// cluster, and the P LDS round-trip hides under 32 back-to-back MFMAs.
// Same-wave DS in-order execution makes the pbuf WAR/RAW safe.
__global__ __launch_bounds__(256, 2) void attn_v8_kernel(
    const unsigned short* __restrict__ Qb, const unsigned short* __restrict__ Kb,
    const unsigned short* __restrict__ Vt, const float* __restrict__ colsum,
    float* __restrict__ out) {
  const int id   = blockIdx.x;        // 0..511
  const int b    = id & 31;
  const int xq   = id >> 5;           // n-block 0..15
  const int wv   = threadIdx.x >> 6;  // 0..3
  const int lane = threadIdx.x & 63;
  const int l15  = lane & 15;
  const int quad = lane >> 4;
  const int nq   = xq * 128 + wv * 32;

  __shared__ unsigned short kbuf[2][64 * 128];  // 2x16 KB: rows m (256B), chunk c^(m&15)
  __shared__ unsigned short vbuf[2][128 * 64];  // 2x16 KB: rows d (128B), chunk c^(d&7)
  __shared__ unsigned short pbuf[4][32 * 40];   // 10 KB: per-wave P^T [n][m32], stride 80B
  __shared__ float cmlb[2][64];                 // per-chunk log2 column denominators

  // Q B-operand: B[col=n=ng*16+l15][k=quad*8+j (+kc*32)] — loop invariant
  bf16x8 qf[2][4];
  #pragma unroll
  for (int ng = 0; ng < 2; ++ng) {
    const unsigned short* Qr =
        Qb + ((size_t)b * N_ + nq + ng * 16 + l15) * D_ + quad * 8;
    #pragma unroll
    for (int kc = 0; kc < 4; ++kc)
      qf[ng][kc] = *reinterpret_cast<const bf16x8*>(Qr + kc * 32);
  }

  // hoisted LDS bases (u16 units)
  const unsigned short* pk[4];   // K read: + cb*8192 + sub*4096 + cg*2048
  #pragma unroll
  for (int kc = 0; kc < 4; ++kc)
    pk[kc] = kbuf[0] + l15 * 128 + (((kc * 4 + quad) ^ l15) * 8);
  const unsigned short* pv[2];   // V read: + cb*8192 + dt*1024
  #pragma unroll
  for (int sub = 0; sub < 2; ++sub)
    pv[sub] = vbuf[0] + l15 * 64 + (((sub * 4 + quad) ^ (l15 & 7)) * 8);
  unsigned short* pww[2];        // P write: + cg*16
  const unsigned short* pwr[2];  // P read
  #pragma unroll
  for (int ng = 0; ng < 2; ++ng) {
    pww[ng] = pbuf[wv] + (ng * 16 + l15) * 40 + quad * 4;
    pwr[ng] = pbuf[wv] + (ng * 16 + l15) * 40 + quad * 8;
  }

  // running DMA source ptrs (4 K + 4 V slots/thread), constant LDS dests
  const unsigned short* kg[4]; unsigned short* kl[4];
  const unsigned short* vg[4]; unsigned short* vl[4];
  #pragma unroll
  for (int i = 0; i < 4; ++i) {
    int s = i * 256 + threadIdx.x;               // 16B slot 0..1023
    int rk = s >> 4, ck = (s & 15) ^ (rk & 15);
    kg[i] = Kb + ((size_t)b * M_ + rk) * D_ + ck * 8;
    kl[i] = kbuf[0] + (size_t)s * 8;
    int rv = s >> 3, cv = (s & 7) ^ (rv & 7);
    vg[i] = Vt + ((size_t)b * D_ + rv) * M_ + cv * 8;
    vl[i] = vbuf[0] + (size_t)s * 8;
  }

  const float* csb = colsum + (size_t)b * M_;

  f32x4 o[2][8];
  #pragma unroll
  for (int ng = 0; ng < 2; ++ng)
    #pragma unroll
    for (int dt = 0; dt < 8; ++dt) o[ng][dt] = (f32x4){0.f, 0.f, 0.f, 0.f};

#define AT_STAGE(nb, chunk)                                                   \
  { _Pragma("unroll")                                                         \
    for (int i = 0; i < 4; ++i) {                                             \
      gl2lds16(kg[i], kl[i] + (nb) * (64 * 128));                             \
      kg[i] += 64 * D_;                                                       \
      gl2lds16(vg[i], vl[i] + (nb) * (128 * 64));                             \
      vg[i] += 64;                                                            \
    }                                                                         \
    if (threadIdx.x < 64)                                                     \
      cmlb[nb][threadIdx.x] =                                                 \
          flog2(csb[(chunk) * 64 + threadIdx.x]) + 16.f; }

  // QK^T (S^T): sacc[cg][ng]: row m = sub*32+cg*16+quad*4+r, col n = ng*16+l15
#define AT_QKT(cb, sub, sacc)                                                 \
  { __builtin_amdgcn_s_setprio(1);                                            \
    _Pragma("unroll")                                                         \
    for (int kc = 0; kc < 4; ++kc) {                                          \
      _Pragma("unroll")                                                       \
      for (int cg = 0; cg < 2; ++cg) {                                        \
        bf16x8 kfr = *reinterpret_cast<const bf16x8*>(                        \
            pk[kc] + (cb) * (64 * 128) + (sub) * 4096 + cg * 2048);           \
        sacc[cg][0] = __builtin_amdgcn_mfma_f32_16x16x32_bf16(                \
            kfr, qf[0][kc], sacc[cg][0], 0, 0, 0);                            \
        sacc[cg][1] = __builtin_amdgcn_mfma_f32_16x16x32_bf16(                \
            kfr, qf[1][kc], sacc[cg][1], 0, 0, 0);                            \
      }                                                                       \
    }                                                                         \
    __builtin_amdgcn_s_setprio(0); }

  // normalized P: w = 2^(s2 - cml[m]); packed b64 of 4 consecutive m
#define AT_SM(cb, sub, sacc)                                                  \
  { _Pragma("unroll")                                                         \
    for (int cg = 0; cg < 2; ++cg) {                                          \
      float4 cm4 = *reinterpret_cast<const float4*>(                          \
          &cmlb[cb][(sub) * 32 + cg * 16 + quad * 4]);                        \
      _Pragma("unroll")                                                       \
      for (int ng = 0; ng < 2; ++ng) {                                        \
        uint2 w;                                                              \
        w.x = pk2bf(fexp2(sacc[cg][ng][0] - cm4.x),                           \
                    fexp2(sacc[cg][ng][1] - cm4.y));                          \
        w.y = pk2bf(fexp2(sacc[cg][ng][2] - cm4.z),                           \
                    fexp2(sacc[cg][ng][3] - cm4.w));                          \
        *reinterpret_cast<uint2*>(pww[ng] + cg * 16) = w;                     \
      }                                                                       \
    } }

  // P A-frags (same-wave LDS RAW, in-order DS) + PV MFMAs
#define AT_PV(cb, sub)                                                        \
  { bf16x8 pa0 = *reinterpret_cast<const bf16x8*>(pwr[0]);                    \
    bf16x8 pa1 = *reinterpret_cast<const bf16x8*>(pwr[1]);                    \
    __builtin_amdgcn_s_setprio(1);                                            \
    _Pragma("unroll")                                                         \
    for (int dt = 0; dt < 8; ++dt) {                                          \
      bf16x8 vfr = *reinterpret_cast<const bf16x8*>(                          \
          pv[sub] + (cb) * (128 * 64) + dt * 1024);                           \
      o[0][dt] = __builtin_amdgcn_mfma_f32_16x16x32_bf16(                     \
          pa0, vfr, o[0][dt], 0, 0, 0);                                       \
      o[1][dt] = __builtin_amdgcn_mfma_f32_16x16x32_bf16(                     \
          pa1, vfr, o[1][dt], 0, 0, 0);                                       \
    }                                                                         \
    __builtin_amdgcn_s_setprio(0); }

  // T15 pipeline: SM(s) and P round-trip overlap the drain of the previously
  // issued MFMA cluster; PV(0) issues behind QKT(1) on the matrix pipe.
#define AT_COMPUTE(cb)                                                        \
  { f32x4 s0_[2][2] = {{{0.f,0.f,0.f,0.f},{0.f,0.f,0.f,0.f}},                 \
                       {{0.f,0.f,0.f,0.f},{0.f,0.f,0.f,0.f}}};                \
    AT_QKT(cb, 0, s0_); AT_SM(cb, 0, s0_);                                    \
    f32x4 s1_[2][2] = {{{0.f,0.f,0.f,0.f},{0.f,0.f,0.f,0.f}},                 \
                       {{0.f,0.f,0.f,0.f},{0.f,0.f,0.f,0.f}}};                \
    AT_QKT(cb, 1, s1_); AT_PV(cb, 0); AT_SM(cb, 1, s1_);                      \
    AT_PV(cb, 1); }

  AT_STAGE(0, 0);
  __syncthreads();
  #pragma unroll 1
  for (int it = 0; it < 32; it += 2) {
    AT_STAGE(1, it + 1);                       // prefetch while computing cur
    AT_COMPUTE(0);
    __syncthreads();                           // next chunk landed; buf0 free
    if (it + 2 < 32) AT_STAGE(0, it + 2);
    AT_COMPUTE(1);
    __syncthreads();
  }
#undef AT_STAGE
#undef AT_QKT
#undef AT_SM
#undef AT_PV
#undef AT_COMPUTE

  // epilogue: o[ng][dt][r] = O[nq + ng*16 + quad*4 + r][dt*16 + l15]
  #pragma unroll
  for (int ng = 0; ng < 2; ++ng)
    #pragma unroll
    for (int dt = 0; dt < 8; ++dt)
      #pragma unroll
      for (int r = 0; r < 4; ++r)
        out[((size_t)b * N_ + nq + ng * 16 + quad * 4 + r) * D_ + dt * 16 + l15] =
            o[ng][dt][r];
}

extern "C" void kernel_launch(void* const* d_in, const int* in_sizes, int n_in,
                              void* d_out, int out_size, void* d_ws, size_t ws_size,
                              hipStream_t stream) {
  const float* Q = (const float*)d_in[0];
  const float* K = (const float*)d_in[1];
  const float* V = (const float*)d_in[2];
  float* out = (float*)d_out;

  const size_t elems = (size_t)B_ * N_ * D_;   // 8,388,608 per tensor
  unsigned short* Qb = (unsigned short*)d_ws;                  // 16 MB
  unsigned short* Kb = Qb + elems;                             // 16 MB
  unsigned short* Vt = Kb + elems;                             // 16 MB
  float* colsum = (float*)(Vt + elems);                        // 256 KB
  // total ws use ~= 48.3 MB (proven safe)

  prep_kernel<<<6144, 256, 0, stream>>>(Q, K, V, Qb, Kb, Vt, colsum);
  colstats_v8_kernel<<<1024, 256, 0, stream>>>(Qb, Kb, colsum);
  attn_v8_kernel<<<512, 256, 0, stream>>>(Qb, Kb, Vt, colsum, out);
}

// Round 3
// 238.721 us; speedup vs baseline: 1.4297x; 1.4297x over previous
//
#include <hip/hip_runtime.h>
#include <hip/hip_bf16.h>

#define B_  32
#define N_  2048
#define M_  2048
#define D_  128

typedef __attribute__((ext_vector_type(4)))  float f32x4;
typedef __attribute__((ext_vector_type(8)))  short bf16x8;

// log2(e) / sqrt(128): softmax in exp2 domain; folded into Q's bf16 cast.
static constexpr float SCALE2 = 1.4426950408889634f / 11.313708498984761f;

__device__ __forceinline__ unsigned short f2bf(float x) {
  union { float f; unsigned u; } c; c.f = x;
  unsigned u = c.u;
  return (unsigned short)((u + 0x7FFFu + ((u >> 16) & 1u)) >> 16);  // RNE
}

__device__ __forceinline__ unsigned pk2bf(float a, float b) {
  float2 f2; f2.x = a; f2.y = b;
  __hip_bfloat162 h = __float22bfloat162_rn(f2);   // v_cvt_pk_bf16_f32
  union { __hip_bfloat162 h; unsigned u; } c; c.h = h;
  return c.u;
}

__device__ __forceinline__ float fexp2(float x) {
#if __has_builtin(__builtin_amdgcn_exp2f)
  return __builtin_amdgcn_exp2f(x);
#else
  float r; asm("v_exp_f32 %0, %1" : "=v"(r) : "v"(x)); return r;
#endif
}
__device__ __forceinline__ float flog2(float x) {
#if __has_builtin(__builtin_amdgcn_logf)
  return __builtin_amdgcn_logf(x);
#else
  float r; asm("v_log_f32 %0, %1" : "=v"(r) : "v"(x)); return r;
#endif
}

// async global->LDS, 16B per lane; LDS dest = wave-uniform base + lane*16
__device__ __forceinline__ void gl2lds16(const void* gp, void* lp) {
  __builtin_amdgcn_global_load_lds(
      (const __attribute__((address_space(1))) unsigned int*)gp,
      (__attribute__((address_space(3))) unsigned int*)lp, 16, 0, 0);
}

// ---------- prep (one dispatch): V transpose FIRST (overlap its LDS/sync
// latency with the cast stream), then cast Q (SCALE2), cast K, zero colsum.
// blocks [0,2048): V transpose; [2048,10240): Q cast; [10240,18432): K cast.
__global__ __launch_bounds__(256) void prep_kernel(
    const float* __restrict__ Q, const float* __restrict__ K,
    const float* __restrict__ V, unsigned short* __restrict__ Qb,
    unsigned short* __restrict__ Kb, unsigned short* __restrict__ Vt,
    float* __restrict__ colsum) {
  const int blk = blockIdx.x;
  if (blk >= 2048) {
    const bool isK = blk >= 10240;
    const int i = (isK ? blk - 10240 : blk - 2048) * 256 + threadIdx.x;
    if (!isK && blk - 2048 < 64) {
      const int j = (blk - 2048) * 256 + threadIdx.x;   // < 16384 == B_*M_/4
      reinterpret_cast<float4*>(colsum)[j] = make_float4(0.f, 0.f, 0.f, 0.f);
    }
    const float4* src = reinterpret_cast<const float4*>(isK ? K : Q);
    uint2* dst = reinterpret_cast<uint2*>(isK ? Kb : Qb);
    const float sc = isK ? 1.0f : SCALE2;
    const float4 v = src[i];
    uint2 o;
    o.x = pk2bf(v.x * sc, v.y * sc);
    o.y = pk2bf(v.z * sc, v.w * sc);
    dst[i] = o;
    return;
  }
  // V transpose: idx -> (b, m0, d0); 2048 blocks = (M/64=32) x (D/64=2) x (B=32)
  const int idx = blk;
  const int b  = idx >> 6;
  const int m0 = ((idx >> 1) & 31) * 64;
  const int d0 = (idx & 1) * 64;
  __shared__ float t[64][65];
  const int tid = threadIdx.x;
  const int r = tid >> 2;   // 0..63
  const int c = tid & 3;    // 0..3
  const float* src = V + ((size_t)b * M_ + (m0 + r)) * D_ + d0 + c * 16;
  #pragma unroll
  for (int i = 0; i < 4; ++i) {
    float4 v = reinterpret_cast<const float4*>(src)[i];
    t[r][c * 16 + i * 4 + 0] = v.x;
    t[r][c * 16 + i * 4 + 1] = v.y;
    t[r][c * 16 + i * 4 + 2] = v.z;
    t[r][c * 16 + i * 4 + 3] = v.w;
  }
  __syncthreads();
  ushort4 ob[4];
  #pragma unroll
  for (int i = 0; i < 4; ++i) {
    ob[i].x = f2bf(t[c * 16 + i * 4 + 0][r]);
    ob[i].y = f2bf(t[c * 16 + i * 4 + 1][r]);
    ob[i].z = f2bf(t[c * 16 + i * 4 + 2][r]);
    ob[i].w = f2bf(t[c * 16 + i * 4 + 3][r]);
  }
  ushort4* dst = reinterpret_cast<ushort4*>(
      Vt + ((size_t)b * D_ + d0 + r) * M_ + m0 + c * 16);
  #pragma unroll
  for (int i = 0; i < 4; ++i) dst[i] = ob[i];
}

// ---------- pass 1: colsum[b][m] += sum_{n in half} 2^(s2[n,m]-16) ----------
// 1024 blocks (4/CU, 16 waves/CU — 2x v7's TLP): id = x*64 + (2b+y), x=m-block
// 0..15 (128 m each, 32 m/wave so kf is only 32 VGPRs -> total demand ~75,
// no spill risk; v8's 64-m/wave + double-acc spilled 200MB to scratch).
// id%8 == (2b+y)%8: the 16 m-blocks sharing a (b, n-half) Q stripe co-reside
// on one XCD (8 stripes x 256KB = 2MB <= 4MB L2). v7's proven single-acc
// 2-phase double-buffered schedule, 16 chunks of 64 n.
__global__ __launch_bounds__(256, 2) void colstats_v9_kernel(
    const unsigned short* __restrict__ Qb, const unsigned short* __restrict__ Kb,
    float* __restrict__ colsum) {
  const int id   = blockIdx.x;          // 0..1023
  const int x    = id >> 6;             // m-block 0..15
  const int q    = id & 63;
  const int b    = q >> 1;
  const int y    = q & 1;               // n-half
  const int lane = threadIdx.x & 63;
  const int l15  = lane & 15;
  const int quad = lane >> 4;
  const int mw   = x * 128 + (threadIdx.x >> 6) * 32;
  const int nbase = y * (N_ / 2);       // 1024-n stripe

  __shared__ unsigned short qbuf[2][64 * 128];  // 2 x 16 KB; rows n, chunk c^(n&15)

  // B-operand: B[col=m=mw+cg*16+l15][k=quad*8+j (+kc*32)] — 32 VGPRs
  bf16x8 kf[2][4];
  #pragma unroll
  for (int cg = 0; cg < 2; ++cg) {
    const unsigned short* Kr =
        Kb + ((size_t)b * M_ + mw + cg * 16 + l15) * D_ + quad * 8;
    #pragma unroll
    for (int kc = 0; kc < 4; ++kc)
      kf[cg][kc] = *reinterpret_cast<const bf16x8*>(Kr + kc * 32);
  }

  // hoisted LDS read bases: addr = pq[kc] + cb*8192 + ng*2048 (u16)
  const unsigned short* pq[4];
  #pragma unroll
  for (int kc = 0; kc < 4; ++kc)
    pq[kc] = qbuf[0] + l15 * 128 + (((kc * 4 + quad) ^ l15) * 8);

  // running DMA source pointers (4 slots/thread), constant LDS dests
  const unsigned short* qg[4];
  unsigned short* ql[4];
  #pragma unroll
  for (int i = 0; i < 4; ++i) {
    int s = i * 256 + threadIdx.x;             // 16B slot 0..1023
    int r = s >> 4, c = (s & 15) ^ (r & 15);
    qg[i] = Qb + ((size_t)b * N_ + nbase + r) * D_ + c * 8;
    ql[i] = qbuf[0] + (size_t)s * 8;           // s*16 bytes
  }

  float psum[2] = {0.f, 0.f};

#define CS_STAGE(nb)                                                          \
  { _Pragma("unroll")                                                         \
    for (int i = 0; i < 4; ++i) {                                             \
      gl2lds16(qg[i], ql[i] + (nb) * (64 * 128));                             \
      qg[i] += 64 * D_;                                                       \
    } }

#define CS_COMPUTE(cb)                                                        \
  { _Pragma("unroll")                                                         \
    for (int ng = 0; ng < 4; ++ng) {                                          \
      f32x4 acc[2] = {{0.f,0.f,0.f,0.f}, {0.f,0.f,0.f,0.f}};                  \
      __builtin_amdgcn_s_setprio(1);                                          \
      _Pragma("unroll")                                                       \
      for (int kc = 0; kc < 4; ++kc) {                                        \
        bf16x8 af = *reinterpret_cast<const bf16x8*>(                         \
            pq[kc] + (cb) * (64 * 128) + ng * 2048);                          \
        _Pragma("unroll")                                                     \
        for (int cg = 0; cg < 2; ++cg)                                        \
          acc[cg] = __builtin_amdgcn_mfma_f32_16x16x32_bf16(                  \
              af, kf[cg][kc], acc[cg], 0, 0, 0);                              \
      }                                                                       \
      __builtin_amdgcn_s_setprio(0);                                          \
      _Pragma("unroll")                                                       \
      for (int cg = 0; cg < 2; ++cg)                                          \
        psum[cg] += fexp2(acc[cg][0] - 16.f) + fexp2(acc[cg][1] - 16.f) +     \
                    fexp2(acc[cg][2] - 16.f) + fexp2(acc[cg][3] - 16.f);      \
    } }

  CS_STAGE(0);                                 // chunk 0
  __syncthreads();
  #pragma unroll 1
  for (int it = 0; it < 16; it += 2) {
    CS_STAGE(1);                               // chunk it+1 (<=15 always)
    CS_COMPUTE(0);
    __syncthreads();                           // chunk it+1 landed; buf0 free
    if (it + 2 < 16) CS_STAGE(0);              // chunk it+2
    CS_COMPUTE(1);
    __syncthreads();
  }
#undef CS_STAGE
#undef CS_COMPUTE

  #pragma unroll
  for (int cg = 0; cg < 2; ++cg) {
    psum[cg] += __shfl_xor(psum[cg], 16);
    psum[cg] += __shfl_xor(psum[cg], 32);
  }
  if (quad == 0) {
    #pragma unroll
    for (int cg = 0; cg < 2; ++cg)
      atomicAdd(colsum + (size_t)b * M_ + mw + cg * 16 + l15, psum[cg]);
  }
}

// ---------- pass 2: O[n,d] = sum_m 2^(s2[n,m]-cml[m]) * Vt[d,m] ----------
// EXACT v7 compute (proven 86.9us; v8's T15 reorder regressed — suspected
// scratch from macro-passed sacc arrays). 512 blocks, XCD-swizzled
// (id%8==b%8 -> FETCH 24.7MB proven). 64-m chunks, double-buffered K/V LDS,
// 2-phase schedule, one barrier per chunk, setprio around MFMA clusters.
__global__ __launch_bounds__(256, 2) void attn_v9_kernel(
    const unsigned short* __restrict__ Qb, const unsigned short* __restrict__ Kb,
    const unsigned short* __restrict__ Vt, const float* __restrict__ colsum,
    float* __restrict__ out) {
  const int id   = blockIdx.x;        // 0..511
  const int b    = id & 31;
  const int xq   = id >> 5;           // n-block 0..15
  const int wv   = threadIdx.x >> 6;  // 0..3
  const int lane = threadIdx.x & 63;
  const int l15  = lane & 15;
  const int quad = lane >> 4;
  const int nq   = xq * 128 + wv * 32;

  __shared__ unsigned short kbuf[2][64 * 128];  // 2x16 KB: rows m (256B), chunk c^(m&15)
  __shared__ unsigned short vbuf[2][128 * 64];  // 2x16 KB: rows d (128B), chunk c^(d&7)
  __shared__ unsigned short pbuf[4][32 * 40];   // 10 KB: per-wave P^T [n][m32], stride 80B
  __shared__ float cmlb[2][64];                 // per-chunk log2 column denominators

  // Q B-operand: B[col=n=ng*16+l15][k=quad*8+j (+kc*32)] — loop invariant
  bf16x8 qf[2][4];
  #pragma unroll
  for (int ng = 0; ng < 2; ++ng) {
    const unsigned short* Qr =
        Qb + ((size_t)b * N_ + nq + ng * 16 + l15) * D_ + quad * 8;
    #pragma unroll
    for (int kc = 0; kc < 4; ++kc)
      qf[ng][kc] = *reinterpret_cast<const bf16x8*>(Qr + kc * 32);
  }

  // hoisted LDS bases (u16 units)
  const unsigned short* pk[4];   // K read: + cb*8192 + sub*4096 + cg*2048
  #pragma unroll
  for (int kc = 0; kc < 4; ++kc)
    pk[kc] = kbuf[0] + l15 * 128 + (((kc * 4 + quad) ^ l15) * 8);
  const unsigned short* pv[2];   // V read: + cb*8192 + dt*1024
  #pragma unroll
  for (int sub = 0; sub < 2; ++sub)
    pv[sub] = vbuf[0] + l15 * 64 + (((sub * 4 + quad) ^ (l15 & 7)) * 8);
  unsigned short* pww[2];        // P write: + cg*16
  const unsigned short* pwr[2];  // P read
  #pragma unroll
  for (int ng = 0; ng < 2; ++ng) {
    pww[ng] = pbuf[wv] + (ng * 16 + l15) * 40 + quad * 4;
    pwr[ng] = pbuf[wv] + (ng * 16 + l15) * 40 + quad * 8;
  }

  // running DMA source ptrs (4 K + 4 V slots/thread), constant LDS dests
  const unsigned short* kg[4]; unsigned short* kl[4];
  const unsigned short* vg[4]; unsigned short* vl[4];
  #pragma unroll
  for (int i = 0; i < 4; ++i) {
    int s = i * 256 + threadIdx.x;               // 16B slot 0..1023
    int rk = s >> 4, ck = (s & 15) ^ (rk & 15);
    kg[i] = Kb + ((size_t)b * M_ + rk) * D_ + ck * 8;
    kl[i] = kbuf[0] + (size_t)s * 8;
    int rv = s >> 3, cv = (s & 7) ^ (rv & 7);
    vg[i] = Vt + ((size_t)b * D_ + rv) * M_ + cv * 8;
    vl[i] = vbuf[0] + (size_t)s * 8;
  }

  const float* csb = colsum + (size_t)b * M_;

  f32x4 o[2][8];
  #pragma unroll
  for (int ng = 0; ng < 2; ++ng)
    #pragma unroll
    for (int dt = 0; dt < 8; ++dt) o[ng][dt] = (f32x4){0.f, 0.f, 0.f, 0.f};

#define AT_STAGE(nb, chunk)                                                   \
  { _Pragma("unroll")                                                         \
    for (int i = 0; i < 4; ++i) {                                             \
      gl2lds16(kg[i], kl[i] + (nb) * (64 * 128));                             \
      kg[i] += 64 * D_;                                                       \
      gl2lds16(vg[i], vl[i] + (nb) * (128 * 64));                             \
      vg[i] += 64;                                                            \
    }                                                                         \
    if (threadIdx.x < 64)                                                     \
      cmlb[nb][threadIdx.x] =                                                 \
          flog2(csb[(chunk) * 64 + threadIdx.x]) + 16.f; }

#define AT_COMPUTE(cb)                                                        \
  { _Pragma("unroll")                                                         \
    for (int sub = 0; sub < 2; ++sub) {                                       \
      /* QK^T (S^T): sacc[cg][ng]: row m=sub*32+cg*16+quad*4+r, col n */      \
      f32x4 sacc[2][2] = {{{0.f,0.f,0.f,0.f},{0.f,0.f,0.f,0.f}},              \
                          {{0.f,0.f,0.f,0.f},{0.f,0.f,0.f,0.f}}};             \
      __builtin_amdgcn_s_setprio(1);                                          \
      _Pragma("unroll")                                                       \
      for (int kc = 0; kc < 4; ++kc) {                                        \
        _Pragma("unroll")                                                     \
        for (int cg = 0; cg < 2; ++cg) {                                      \
          bf16x8 kfr = *reinterpret_cast<const bf16x8*>(                      \
              pk[kc] + (cb) * (64 * 128) + sub * 4096 + cg * 2048);           \
          sacc[cg][0] = __builtin_amdgcn_mfma_f32_16x16x32_bf16(              \
              kfr, qf[0][kc], sacc[cg][0], 0, 0, 0);                          \
          sacc[cg][1] = __builtin_amdgcn_mfma_f32_16x16x32_bf16(              \
              kfr, qf[1][kc], sacc[cg][1], 0, 0, 0);                          \
        }                                                                     \
      }                                                                       \
      __builtin_amdgcn_s_setprio(0);                                          \
      /* normalized P: w = 2^(s2 - cml[m]); packed b64 of 4 consecutive m */  \
      _Pragma("unroll")                                                       \
      for (int cg = 0; cg < 2; ++cg) {                                        \
        float4 cm4 = *reinterpret_cast<const float4*>(                        \
            &cmlb[cb][sub * 32 + cg * 16 + quad * 4]);                        \
        _Pragma("unroll")                                                     \
        for (int ng = 0; ng < 2; ++ng) {                                      \
          uint2 w;                                                            \
          w.x = pk2bf(fexp2(sacc[cg][ng][0] - cm4.x),                         \
                      fexp2(sacc[cg][ng][1] - cm4.y));                        \
          w.y = pk2bf(fexp2(sacc[cg][ng][2] - cm4.z),                         \
                      fexp2(sacc[cg][ng][3] - cm4.w));                        \
          *reinterpret_cast<uint2*>(pww[ng] + cg * 16) = w;                   \
        }                                                                     \
      }                                                                       \
      /* P A-frags (same-wave LDS RAW; lgkmcnt ordered) */                    \
      bf16x8 pa0 = *reinterpret_cast<const bf16x8*>(pwr[0]);                  \
      bf16x8 pa1 = *reinterpret_cast<const bf16x8*>(pwr[1]);                  \
      __builtin_amdgcn_s_setprio(1);                                          \
      _Pragma("unroll")                                                       \
      for (int dt = 0; dt < 8; ++dt) {                                        \
        bf16x8 vfr = *reinterpret_cast<const bf16x8*>(                        \
            pv[sub] + (cb) * (128 * 64) + dt * 1024);                         \
        o[0][dt] = __builtin_amdgcn_mfma_f32_16x16x32_bf16(                   \
            pa0, vfr, o[0][dt], 0, 0, 0);                                     \
        o[1][dt] = __builtin_amdgcn_mfma_f32_16x16x32_bf16(                   \
            pa1, vfr, o[1][dt], 0, 0, 0);                                     \
      }                                                                       \
      __builtin_amdgcn_s_setprio(0);                                          \
    } }

  AT_STAGE(0, 0);
  __syncthreads();
  #pragma unroll 1
  for (int it = 0; it < 32; it += 2) {
    AT_STAGE(1, it + 1);                       // prefetch while computing cur
    AT_COMPUTE(0);
    __syncthreads();                           // next chunk landed; buf0 free
    if (it + 2 < 32) AT_STAGE(0, it + 2);
    AT_COMPUTE(1);
    __syncthreads();
  }
#undef AT_STAGE
#undef AT_COMPUTE

  // epilogue: o[ng][dt][r] = O[nq + ng*16 + quad*4 + r][dt*16 + l15]
  #pragma unroll
  for (int ng = 0; ng < 2; ++ng)
    #pragma unroll
    for (int dt = 0; dt < 8; ++dt)
      #pragma unroll
      for (int r = 0; r < 4; ++r)
        out[((size_t)b * N_ + nq + ng * 16 + quad * 4 + r) * D_ + dt * 16 + l15] =
            o[ng][dt][r];
}

extern "C" void kernel_launch(void* const* d_in, const int* in_sizes, int n_in,
                              void* d_out, int out_size, void* d_ws, size_t ws_size,
                              hipStream_t stream) {
  const float* Q = (const float*)d_in[0];
  const float* K = (const float*)d_in[1];
  const float* V = (const float*)d_in[2];
  float* out = (float*)d_out;

  const size_t elems = (size_t)B_ * N_ * D_;   // 8,388,608 per tensor
  unsigned short* Qb = (unsigned short*)d_ws;                  // 16 MB
  unsigned short* Kb = Qb + elems;                             // 16 MB
  unsigned short* Vt = Kb + elems;                             // 16 MB
  float* colsum = (float*)(Vt + elems);                        // 256 KB
  // total ws use ~= 48.3 MB (proven safe)

  prep_kernel<<<18432, 256, 0, stream>>>(Q, K, V, Qb, Kb, Vt, colsum);
  colstats_v9_kernel<<<1024, 256, 0, stream>>>(Qb, Kb, colsum);
  attn_v9_kernel<<<512, 256, 0, stream>>>(Qb, Kb, Vt, colsum, out);
}